// Round 1
// baseline (344.470 us; speedup 1.0000x reference)
//
#include <hip/hip_runtime.h>
#include <hip/hip_bf16.h>

#define BATCH 16384
#define K1 3237
#define K1P 3264
#define NH 1024
#define NF 39
#define CCLD 72

typedef __attribute__((ext_vector_type(8))) short bf16x8;
typedef __attribute__((ext_vector_type(4))) float f32x4;

typedef const __attribute__((address_space(1))) unsigned int* gptr_t;
typedef __attribute__((address_space(3))) unsigned int* lptr_t;

__device__ __forceinline__ float bf2f(unsigned short u) {
  union { unsigned int i; float f; } c; c.i = ((unsigned int)u) << 16; return c.f;
}
__device__ __forceinline__ unsigned short f2bf(float f) {
  union { float f; unsigned int i; } c; c.f = f;
  unsigned int r = c.i + 0x7FFFu + ((c.i >> 16) & 1u);
  return (unsigned short)(r >> 16);
}

// ---- W transpose + bf16 cast: src (K x N f32) -> dst (N x Kpad bf16), zero for k>=K
__global__ __launch_bounds__(256) void transpose_cast_kernel(
    const float* __restrict__ src, unsigned short* __restrict__ dst,
    int K, int N, int Kpad) {
  __shared__ float tile[32][33];
  int kb = blockIdx.x * 32, nb = blockIdx.y * 32;
  int tx = threadIdx.x & 31, ty = threadIdx.x >> 5;
#pragma unroll
  for (int i = 0; i < 32; i += 8) {
    int k = kb + ty + i;
    tile[ty + i][tx] = (k < K) ? src[(size_t)k * N + nb + tx] : 0.f;
  }
  __syncthreads();
#pragma unroll
  for (int i = 0; i < 32; i += 8) {
    int n = nb + ty + i, k = kb + tx;
    dst[(size_t)n * Kpad + k] = f2bf(tile[tx][ty + i]);
  }
}

// ---- features: cc (39x64) per row -> X[0:2496] flat + X[2496:3237] gram pairs, pad zeroed
__global__ __launch_bounds__(256) void feature_kernel(
    const float* __restrict__ conts, const int* __restrict__ cates,
    const float* __restrict__ emb, unsigned short* __restrict__ X) {
  __shared__ unsigned short cc[4][48 * CCLD];
  int wid = threadIdx.x >> 6, lane = threadIdx.x & 63;
  int b = (blockIdx.x << 2) | wid;
  unsigned short* my = cc[wid];
  unsigned short* Xrow = X + (size_t)b * K1P;

#pragma unroll
  for (int f = 0; f < 13; ++f) {
    float v = emb[f * 64 + lane] * conts[b * 13 + f];
    unsigned short u = f2bf(v);
    my[f * CCLD + lane] = u;
    Xrow[f * 64 + lane] = u;
  }
#pragma unroll 2
  for (int j = 0; j < 26; ++j) {
    int idx = cates[b * 26 + j];
    float v = emb[(size_t)idx * 64 + lane];
    unsigned short u = f2bf(v);
    my[(13 + j) * CCLD + lane] = u;
    Xrow[(13 + j) * 64 + lane] = u;
  }
#pragma unroll
  for (int f = NF; f < 48; ++f) my[f * CCLD + lane] = 0;
  if (lane < K1P - K1) Xrow[K1 + lane] = 0;
  __syncthreads();

  int r15 = lane & 15, hi = lane >> 4;
  bf16x8 fr[2][3];
#pragma unroll
  for (int t = 0; t < 3; ++t)
#pragma unroll
    for (int h = 0; h < 2; ++h)
      fr[h][t] = *(const bf16x8*)&my[(t * 16 + r15) * CCLD + h * 32 + hi * 8];

  f32x4 acc[3][3];
#pragma unroll
  for (int it = 0; it < 3; ++it)
#pragma unroll
    for (int jt = 0; jt < 3; ++jt)
      acc[it][jt] = (f32x4){0.f, 0.f, 0.f, 0.f};

#pragma unroll
  for (int h = 0; h < 2; ++h)
#pragma unroll
    for (int it = 0; it < 3; ++it)
#pragma unroll
      for (int jt = 0; jt < 3; ++jt)
        acc[it][jt] = __builtin_amdgcn_mfma_f32_16x16x32_bf16(
            fr[h][it], fr[h][jt], acc[it][jt], 0, 0, 0);

  // C/D layout: col = lane&15, row = (lane>>4)*4 + r  [m89/m91]
#pragma unroll
  for (int it = 0; it < 3; ++it)
#pragma unroll
    for (int jt = 0; jt < 3; ++jt) {
      int g = jt * 16 + r15;
#pragma unroll
      for (int r = 0; r < 4; ++r) {
        int f = it * 16 + hi * 4 + r;
        if (f < g && g < NF) {
          int p = f * 38 - ((f * (f - 1)) >> 1) + g - f - 1;
          Xrow[2496 + p] = f2bf(acc[it][jt][r]);
        }
      }
    }
}

// ---- m97-style bf16 GEMM: C(MxN f32) = A(MxK) * Bt(NxK)^T, 128x128 tile, BK=32
__global__ __launch_bounds__(256) void gemm_bt(
    const unsigned short* __restrict__ A, const unsigned short* __restrict__ Bt,
    float* __restrict__ C, int K, int nbx) {
  __shared__ unsigned short As[128 * 32];
  __shared__ unsigned short Bs[128 * 32];

  int nwg = gridDim.x;
  int per = nwg >> 3;
  int bid = blockIdx.x;
  int swz = (bid & 7) * per + (bid >> 3);  // XCD-chunked swizzle (nwg % 8 == 0)
  int mb = swz / nbx, nb = swz - mb * nbx;
  size_t m0 = (size_t)mb * 128, n0 = (size_t)nb * 128;

  int tid = threadIdx.x;
  int lane = tid & 63, wid = tid >> 6;
  int wr = wid >> 1, wc = wid & 1;
  int r15 = lane & 15, hi = lane >> 4;

  int o1 = tid * 16;        // byte offset in 8192B tile
  int o2 = o1 + 4096;
  int r1 = o1 >> 6, c1 = (o1 & 63) >> 1;
  int r2 = o2 >> 6, c2 = (o2 & 63) >> 1;

  const unsigned short* a1p = A + (m0 + r1) * K + c1;
  const unsigned short* a2p = A + (m0 + r2) * K + c2;
  const unsigned short* b1p = Bt + (n0 + r1) * K + c1;
  const unsigned short* b2p = Bt + (n0 + r2) * K + c2;

  f32x4 acc[4][4];
#pragma unroll
  for (int m = 0; m < 4; ++m)
#pragma unroll
    for (int n = 0; n < 4; ++n) acc[m][n] = (f32x4){0.f, 0.f, 0.f, 0.f};

  for (int k0 = 0; k0 < K; k0 += 32) {
    __builtin_amdgcn_global_load_lds((gptr_t)(a1p + k0), (lptr_t)((lptr_t)As + (o1 >> 2)), 16, 0, 0);
    __builtin_amdgcn_global_load_lds((gptr_t)(a2p + k0), (lptr_t)((lptr_t)As + (o2 >> 2)), 16, 0, 0);
    __builtin_amdgcn_global_load_lds((gptr_t)(b1p + k0), (lptr_t)((lptr_t)Bs + (o1 >> 2)), 16, 0, 0);
    __builtin_amdgcn_global_load_lds((gptr_t)(b2p + k0), (lptr_t)((lptr_t)Bs + (o2 >> 2)), 16, 0, 0);
    __syncthreads();

    bf16x8 af[4], bfr[4];
#pragma unroll
    for (int m = 0; m < 4; ++m)
      af[m] = *(const bf16x8*)&As[(wr * 64 + m * 16 + r15) * 32 + hi * 8];
#pragma unroll
    for (int n = 0; n < 4; ++n)
      bfr[n] = *(const bf16x8*)&Bs[(wc * 64 + n * 16 + r15) * 32 + hi * 8];
#pragma unroll
    for (int m = 0; m < 4; ++m)
#pragma unroll
      for (int n = 0; n < 4; ++n)
        acc[m][n] = __builtin_amdgcn_mfma_f32_16x16x32_bf16(af[m], bfr[n], acc[m][n], 0, 0, 0);
    __syncthreads();
  }

  int N = nbx * 128;
#pragma unroll
  for (int m = 0; m < 4; ++m)
#pragma unroll
    for (int n = 0; n < 4; ++n) {
      size_t row = m0 + wr * 64 + m * 16 + hi * 4;
      size_t col = n0 + wc * 64 + n * 16 + r15;
#pragma unroll
      for (int r = 0; r < 4; ++r)
        C[(row + r) * N + col] = acc[m][n][r];
    }
}

// ---- bias + layernorm + relu + bf16 cast, one block per row (N=1024)
__global__ __launch_bounds__(256) void ln_relu_kernel(
    const float* __restrict__ Y, const float* __restrict__ bias,
    const float* __restrict__ gamma, const float* __restrict__ beta,
    unsigned short* __restrict__ H) {
  int b = blockIdx.x, tid = threadIdx.x;
  float4 v = ((const float4*)(Y + (size_t)b * NH))[tid];
  float4 bb = ((const float4*)bias)[tid];
  v.x += bb.x; v.y += bb.y; v.z += bb.z; v.w += bb.w;
  float s1 = v.x + v.y + v.z + v.w;
  float s2 = v.x * v.x + v.y * v.y + v.z * v.z + v.w * v.w;
#pragma unroll
  for (int i = 1; i < 64; i <<= 1) {
    s1 += __shfl_xor(s1, i);
    s2 += __shfl_xor(s2, i);
  }
  __shared__ float a1[4], a2[4];
  int wid = tid >> 6, lane = tid & 63;
  if (lane == 0) { a1[wid] = s1; a2[wid] = s2; }
  __syncthreads();
  s1 = a1[0] + a1[1] + a1[2] + a1[3];
  s2 = a2[0] + a2[1] + a2[2] + a2[3];
  float mu = s1 * (1.0f / NH);
  float var = s2 * (1.0f / NH) - mu * mu;
  float rs = rsqrtf(var + 1e-5f);
  float4 gg = ((const float4*)gamma)[tid];
  float4 be = ((const float4*)beta)[tid];
  float o0 = fmaxf((v.x - mu) * rs * gg.x + be.x, 0.f);
  float o1 = fmaxf((v.y - mu) * rs * gg.y + be.y, 0.f);
  float o2 = fmaxf((v.z - mu) * rs * gg.z + be.z, 0.f);
  float o3 = fmaxf((v.w - mu) * rs * gg.w + be.w, 0.f);
  ushort4 w;
  w.x = f2bf(o0); w.y = f2bf(o1); w.z = f2bf(o2); w.w = f2bf(o3);
  ((ushort4*)(H + (size_t)b * NH))[tid] = w;
}

// ---- final GEMV + sigmoid: one wave per row
__global__ __launch_bounds__(256) void out_kernel(
    const unsigned short* __restrict__ H, const float* __restrict__ Wout,
    const float* __restrict__ bout, float* __restrict__ out) {
  int wid = threadIdx.x >> 6, lane = threadIdx.x & 63;
  int b = (blockIdx.x << 2) | wid;
  const unsigned short* h = H + (size_t)b * NH + lane * 16;
  float s = 0.f;
#pragma unroll
  for (int i = 0; i < 16; ++i) s += bf2f(h[i]) * Wout[lane * 16 + i];
#pragma unroll
  for (int i = 1; i < 64; i <<= 1) s += __shfl_xor(s, i);
  if (lane == 0) out[b] = 1.f / (1.f + expf(-(s + bout[0])));
}

extern "C" void kernel_launch(void* const* d_in, const int* in_sizes, int n_in,
                              void* d_out, int out_size, void* d_ws, size_t ws_size,
                              hipStream_t stream) {
  const float* conts = (const float*)d_in[0];
  const int* cates = (const int*)d_in[1];
  // d_in[2] = combs (unused by reference)
  const float* emb  = (const float*)d_in[3];
  const float* W1   = (const float*)d_in[4];
  const float* b1   = (const float*)d_in[5];
  const float* ln1g = (const float*)d_in[6];
  const float* ln1b = (const float*)d_in[7];
  const float* W2   = (const float*)d_in[8];
  const float* b2   = (const float*)d_in[9];
  const float* ln2g = (const float*)d_in[10];
  const float* ln2b = (const float*)d_in[11];
  const float* Wout = (const float*)d_in[12];
  const float* bout = (const float*)d_in[13];
  float* out = (float*)d_out;

  unsigned short* X   = (unsigned short*)d_ws;            // BATCH * K1P
  unsigned short* W1t = X + (size_t)BATCH * K1P;          // NH * K1P
  unsigned short* W2t = W1t + (size_t)NH * K1P;           // NH * NH
  unsigned short* H1  = W2t + (size_t)NH * NH;            // BATCH * NH
  unsigned short* H2  = H1 + (size_t)BATCH * NH;          // BATCH * NH
  float* Y = (float*)(H2 + (size_t)BATCH * NH);           // BATCH * NH f32

  hipLaunchKernelGGL(transpose_cast_kernel, dim3(K1P / 32, NH / 32), dim3(256), 0, stream,
                     W1, W1t, K1, NH, K1P);
  hipLaunchKernelGGL(transpose_cast_kernel, dim3(NH / 32, NH / 32), dim3(256), 0, stream,
                     W2, W2t, NH, NH, NH);
  hipLaunchKernelGGL(feature_kernel, dim3(BATCH / 4), dim3(256), 0, stream,
                     conts, cates, emb, X);
  hipLaunchKernelGGL(gemm_bt, dim3((BATCH / 128) * (NH / 128)), dim3(256), 0, stream,
                     X, W1t, Y, K1P, NH / 128);
  hipLaunchKernelGGL(ln_relu_kernel, dim3(BATCH), dim3(256), 0, stream,
                     Y, b1, ln1g, ln1b, H1);
  hipLaunchKernelGGL(gemm_bt, dim3((BATCH / 128) * (NH / 128)), dim3(256), 0, stream,
                     H1, W2t, Y, NH, NH / 128);
  hipLaunchKernelGGL(ln_relu_kernel, dim3(BATCH), dim3(256), 0, stream,
                     Y, b2, ln2g, ln2b, H2);
  hipLaunchKernelGGL(out_kernel, dim3(BATCH / 4), dim3(256), 0, stream,
                     H2, Wout, bout, out);
}

// Round 2
// 245.589 us; speedup vs baseline: 1.4026x; 1.4026x over previous
//
#include <hip/hip_runtime.h>
#include <hip/hip_bf16.h>

#define BATCH 16384
#define K1 3237
#define K1P 3264
#define NH 1024
#define NF 39
#define CCLD 72

typedef __attribute__((ext_vector_type(8))) short bf16x8;
typedef __attribute__((ext_vector_type(4))) float f32x4;

typedef const __attribute__((address_space(1))) unsigned int* gptr_t;
typedef __attribute__((address_space(3))) unsigned int* lptr_t;

__device__ __forceinline__ float bf2f(unsigned short u) {
  union { unsigned int i; float f; } c; c.i = ((unsigned int)u) << 16; return c.f;
}
__device__ __forceinline__ unsigned short f2bf(float f) {
  union { float f; unsigned int i; } c; c.f = f;
  unsigned int r = c.i + 0x7FFFu + ((c.i >> 16) & 1u);
  return (unsigned short)(r >> 16);
}

// ---- W transpose + bf16 cast: src (K x N f32) -> dst (N x Kpad bf16), zero for k>=K
__global__ __launch_bounds__(256) void transpose_cast_kernel(
    const float* __restrict__ src, unsigned short* __restrict__ dst,
    int K, int N, int Kpad) {
  __shared__ float tile[32][33];
  int kb = blockIdx.x * 32, nb = blockIdx.y * 32;
  int tx = threadIdx.x & 31, ty = threadIdx.x >> 5;
#pragma unroll
  for (int i = 0; i < 32; i += 8) {
    int k = kb + ty + i;
    tile[ty + i][tx] = (k < K) ? src[(size_t)k * N + nb + tx] : 0.f;
  }
  __syncthreads();
#pragma unroll
  for (int i = 0; i < 32; i += 8) {
    int n = nb + ty + i, k = kb + tx;
    dst[(size_t)n * Kpad + k] = f2bf(tile[tx][ty + i]);
  }
}

// ---- features: cc (39x64) per row -> X[0:2496] flat + X[2496:3237] gram pairs, pad zeroed
__global__ __launch_bounds__(256) void feature_kernel(
    const float* __restrict__ conts, const int* __restrict__ cates,
    const float* __restrict__ emb, unsigned short* __restrict__ X) {
  __shared__ unsigned short cc[4][48 * CCLD];
  int wid = threadIdx.x >> 6, lane = threadIdx.x & 63;
  int b = (blockIdx.x << 2) | wid;
  unsigned short* my = cc[wid];
  unsigned short* Xrow = X + (size_t)b * K1P;

#pragma unroll
  for (int f = 0; f < 13; ++f) {
    float v = emb[f * 64 + lane] * conts[b * 13 + f];
    unsigned short u = f2bf(v);
    my[f * CCLD + lane] = u;
    Xrow[f * 64 + lane] = u;
  }
#pragma unroll 2
  for (int j = 0; j < 26; ++j) {
    int idx = cates[b * 26 + j];
    float v = emb[(size_t)idx * 64 + lane];
    unsigned short u = f2bf(v);
    my[(13 + j) * CCLD + lane] = u;
    Xrow[(13 + j) * 64 + lane] = u;
  }
#pragma unroll
  for (int f = NF; f < 48; ++f) my[f * CCLD + lane] = 0;
  if (lane < K1P - K1) Xrow[K1 + lane] = 0;
  __syncthreads();

  int r15 = lane & 15, hi = lane >> 4;
  bf16x8 fr[2][3];
#pragma unroll
  for (int t = 0; t < 3; ++t)
#pragma unroll
    for (int h = 0; h < 2; ++h)
      fr[h][t] = *(const bf16x8*)&my[(t * 16 + r15) * CCLD + h * 32 + hi * 8];

  f32x4 acc[3][3];
#pragma unroll
  for (int it = 0; it < 3; ++it)
#pragma unroll
    for (int jt = 0; jt < 3; ++jt)
      acc[it][jt] = (f32x4){0.f, 0.f, 0.f, 0.f};

#pragma unroll
  for (int h = 0; h < 2; ++h)
#pragma unroll
    for (int it = 0; it < 3; ++it)
#pragma unroll
      for (int jt = 0; jt < 3; ++jt)
        acc[it][jt] = __builtin_amdgcn_mfma_f32_16x16x32_bf16(
            fr[h][it], fr[h][jt], acc[it][jt], 0, 0, 0);

#pragma unroll
  for (int it = 0; it < 3; ++it)
#pragma unroll
    for (int jt = 0; jt < 3; ++jt) {
      int g = jt * 16 + r15;
#pragma unroll
      for (int r = 0; r < 4; ++r) {
        int f = it * 16 + hi * 4 + r;
        if (f < g && g < NF) {
          int p = f * 38 - ((f * (f - 1)) >> 1) + g - f - 1;
          Xrow[2496 + p] = f2bf(acc[it][jt][r]);
        }
      }
    }
}

// ===================== 256x256 8-phase GEMM (T1+T2+T3+T4+T5) =====================
// C(16384 x 1024 f32) = A(16384 x K bf16) * Bt(1024 x K bf16)^T, K multiple of 64.
// 8 waves (2M x 4N), per-wave 128x64 output. LDS: [buf2][matA/B][half2][128x64 bf16]
// = 128 KiB. XOR-swizzle byte^=((row&7)<<4) on ds_read; inverse-swizzled global
// source for global_load_lds (linear LDS dest). vmcnt(4) once per K-tile.

#define GLL(s_, d_) __builtin_amdgcn_global_load_lds((gptr_t)(s_), (lptr_t)(d_), 16, 0, 0)
#define RD(p_) (*(const bf16x8*)(p_))
#define DSTA(buf, h) (lds + (buf) * 32768 + (h) * 8192 + sd)
#define DSTB(buf, h) (lds + (buf) * 32768 + 16384 + (h) * 8192 + sd)
#define STG(dst, srcb, tau) do { \
    const unsigned short* _s = (srcb) + (size_t)(tau) * 64; \
    GLL(_s, dst); GLL(_s + (size_t)64 * K, (dst) + 4096); } while (0)
#define PHASE_BAR() do { \
    __builtin_amdgcn_s_barrier(); \
    asm volatile("s_waitcnt lgkmcnt(0)" ::: "memory"); \
    __builtin_amdgcn_sched_barrier(0); \
    __builtin_amdgcn_s_setprio(1); } while (0)
#define PHASE_END() do { \
    __builtin_amdgcn_s_setprio(0); \
    __builtin_amdgcn_s_barrier(); \
    __builtin_amdgcn_sched_barrier(0); } while (0)

__global__ __launch_bounds__(512, 2) void gemm_8ph(
    const unsigned short* __restrict__ A, const unsigned short* __restrict__ Bt,
    float* __restrict__ C, int K, int NT) {
  __shared__ unsigned short lds[65536];  // 128 KiB

  int bid = blockIdx.x;
  int swz = (bid & 7) * 32 + (bid >> 3);  // 256 wgs, 8 XCDs, chunked (bijective)
  int mb = swz >> 2, nb = swz & 3;
  size_t m0 = (size_t)mb * 256, n0 = (size_t)nb * 256;

  int tid = threadIdx.x, lane = tid & 63, w = tid >> 6;
  int wr = w >> 2, wc = w & 3;
  int r15 = lane & 15, hi = lane >> 4;

  // staging constants: thread covers rows sr, sr+64 of a half; col group ce is
  // the inverse swizzle of its linear LDS slot.
  int sr = tid >> 3;
  int ce = ((tid & 7) ^ (sr & 7)) << 3;
  int sd = tid * 8;  // shorts
  const unsigned short* A0p = A + (m0 + sr) * (size_t)K + ce;
  const unsigned short* A1p = A0p + (size_t)128 * K;
  const unsigned short* B0p = Bt + (n0 + sr) * (size_t)K + ce;
  const unsigned short* B1p = B0p + (size_t)128 * K;

  // read-side swizzled lane offsets (shorts)
  int cbs = (((hi << 4) ^ ((r15 & 7) << 4)) >> 1);
  int rb0 = r15 * 64 + cbs;
  int rb1 = rb0 ^ 32;
  const unsigned short* aH = lds + wr * 8192;
  const unsigned short* bH = lds + 16384 + (wc >> 1) * 8192 + (wc & 1) * 4096;

  f32x4 acc[8][4];
#pragma unroll
  for (int m = 0; m < 8; ++m)
#pragma unroll
    for (int n = 0; n < 4; ++n) acc[m][n] = (f32x4){0.f, 0.f, 0.f, 0.f};

  // ---- prologue: B(0),A(0),B(1) staged; allow last 2 half-tiles in flight
  {
    int t1 = (NT > 1) ? 1 : 0;
    STG(DSTB(0, 0), B0p, 0);
    STG(DSTB(0, 1), B1p, 0);
    STG(DSTA(0, 0), A0p, 0);
    STG(DSTA(0, 1), A1p, 0);
    STG(DSTB(1, 0), B0p, t1);
    STG(DSTB(1, 1), B1p, t1);
    asm volatile("s_waitcnt vmcnt(4)" ::: "memory");
    __builtin_amdgcn_s_barrier();
    __builtin_amdgcn_sched_barrier(0);
  }

  bf16x8 aF[4][2], bF[4][2];

  for (int t = 0; t < NT; ++t) {
    int cur = t & 1, nxt = cur ^ 1;
    int ta = (t + 1 < NT) ? t + 1 : NT - 1;  // clamped (dummy stagings stay in-bounds)
    int tb = (t + 2 < NT) ? t + 2 : NT - 1;
    const unsigned short* aB = aH + cur * 32768;
    const unsigned short* bB = bH + cur * 32768;

    // ---- phase 0: read A frags 0-3 + B frags 0-1; stage A-half0(t+1); MFMA (m0-3, n0-1)
#pragma unroll
    for (int i = 0; i < 4; ++i) {
      aF[i][0] = RD(aB + i * 1024 + rb0);
      aF[i][1] = RD(aB + i * 1024 + rb1);
    }
#pragma unroll
    for (int j = 0; j < 2; ++j) {
      bF[j][0] = RD(bB + j * 1024 + rb0);
      bF[j][1] = RD(bB + j * 1024 + rb1);
    }
    STG(DSTA(nxt, 0), A0p, ta);
    PHASE_BAR();
#pragma unroll
    for (int i = 0; i < 4; ++i)
#pragma unroll
      for (int j = 0; j < 2; ++j) {
        acc[i][j] = __builtin_amdgcn_mfma_f32_16x16x32_bf16(aF[i][0], bF[j][0], acc[i][j], 0, 0, 0);
        acc[i][j] = __builtin_amdgcn_mfma_f32_16x16x32_bf16(aF[i][1], bF[j][1], acc[i][j], 0, 0, 0);
      }
    PHASE_END();

    // ---- phase 1: read B frags 2-3; stage A-half1(t+1); MFMA (m0-3, n2-3)
#pragma unroll
    for (int j = 0; j < 2; ++j) {
      bF[2 + j][0] = RD(bB + (2 + j) * 1024 + rb0);
      bF[2 + j][1] = RD(bB + (2 + j) * 1024 + rb1);
    }
    STG(DSTA(nxt, 1), A1p, ta);
    PHASE_BAR();
#pragma unroll
    for (int i = 0; i < 4; ++i)
#pragma unroll
      for (int j = 0; j < 2; ++j) {
        acc[i][2 + j] = __builtin_amdgcn_mfma_f32_16x16x32_bf16(aF[i][0], bF[2 + j][0], acc[i][2 + j], 0, 0, 0);
        acc[i][2 + j] = __builtin_amdgcn_mfma_f32_16x16x32_bf16(aF[i][1], bF[2 + j][1], acc[i][2 + j], 0, 0, 0);
      }
    PHASE_END();

    // ---- phase 2: read A frags 4-7; stage B-half0(t+2) (B reads done in ph1); MFMA (m4-7, n2-3)
#pragma unroll
    for (int i = 0; i < 4; ++i) {
      aF[i][0] = RD(aB + (4 + i) * 1024 + rb0);
      aF[i][1] = RD(aB + (4 + i) * 1024 + rb1);
    }
    STG(DSTB(cur, 0), B0p, tb);
    PHASE_BAR();
#pragma unroll
    for (int i = 0; i < 4; ++i)
#pragma unroll
      for (int j = 0; j < 2; ++j) {
        acc[4 + i][2 + j] = __builtin_amdgcn_mfma_f32_16x16x32_bf16(aF[i][0], bF[2 + j][0], acc[4 + i][2 + j], 0, 0, 0);
        acc[4 + i][2 + j] = __builtin_amdgcn_mfma_f32_16x16x32_bf16(aF[i][1], bF[2 + j][1], acc[4 + i][2 + j], 0, 0, 0);
      }
    PHASE_END();

    // ---- phase 3: stage B-half1(t+2); tile-boundary vmcnt(4); MFMA (m4-7, n0-1)
    STG(DSTB(cur, 1), B1p, tb);
    asm volatile("s_waitcnt vmcnt(4)" ::: "memory");
    PHASE_BAR();
#pragma unroll
    for (int i = 0; i < 4; ++i)
#pragma unroll
      for (int j = 0; j < 2; ++j) {
        acc[4 + i][j] = __builtin_amdgcn_mfma_f32_16x16x32_bf16(aF[i][0], bF[j][0], acc[4 + i][j], 0, 0, 0);
        acc[4 + i][j] = __builtin_amdgcn_mfma_f32_16x16x32_bf16(aF[i][1], bF[j][1], acc[4 + i][j], 0, 0, 0);
      }
    PHASE_END();
  }

  // ---- epilogue: C/D layout col=lane&15, row=(lane>>4)*4+q
  size_t crow = m0 + (size_t)wr * 128 + hi * 4;
  size_t ccol = n0 + (size_t)wc * 64 + r15;
  float* Cp = C + crow * NH + ccol;
#pragma unroll
  for (int m = 0; m < 8; ++m)
#pragma unroll
    for (int n = 0; n < 4; ++n)
#pragma unroll
      for (int q = 0; q < 4; ++q)
        Cp[(size_t)(m * 16 + q) * NH + n * 16] = acc[m][n][q];
}

// ---- bias + layernorm + relu + bf16 cast, one block per row (N=1024)
__global__ __launch_bounds__(256) void ln_relu_kernel(
    const float* __restrict__ Y, const float* __restrict__ bias,
    const float* __restrict__ gamma, const float* __restrict__ beta,
    unsigned short* __restrict__ H) {
  int b = blockIdx.x, tid = threadIdx.x;
  float4 v = ((const float4*)(Y + (size_t)b * NH))[tid];
  float4 bb = ((const float4*)bias)[tid];
  v.x += bb.x; v.y += bb.y; v.z += bb.z; v.w += bb.w;
  float s1 = v.x + v.y + v.z + v.w;
  float s2 = v.x * v.x + v.y * v.y + v.z * v.z + v.w * v.w;
#pragma unroll
  for (int i = 1; i < 64; i <<= 1) {
    s1 += __shfl_xor(s1, i);
    s2 += __shfl_xor(s2, i);
  }
  __shared__ float a1[4], a2[4];
  int wid = tid >> 6, lane = tid & 63;
  if (lane == 0) { a1[wid] = s1; a2[wid] = s2; }
  __syncthreads();
  s1 = a1[0] + a1[1] + a1[2] + a1[3];
  s2 = a2[0] + a2[1] + a2[2] + a2[3];
  float mu = s1 * (1.0f / NH);
  float var = s2 * (1.0f / NH) - mu * mu;
  float rs = rsqrtf(var + 1e-5f);
  float4 gg = ((const float4*)gamma)[tid];
  float4 be = ((const float4*)beta)[tid];
  float o0 = fmaxf((v.x - mu) * rs * gg.x + be.x, 0.f);
  float o1 = fmaxf((v.y - mu) * rs * gg.y + be.y, 0.f);
  float o2 = fmaxf((v.z - mu) * rs * gg.z + be.z, 0.f);
  float o3 = fmaxf((v.w - mu) * rs * gg.w + be.w, 0.f);
  ushort4 wv;
  wv.x = f2bf(o0); wv.y = f2bf(o1); wv.z = f2bf(o2); wv.w = f2bf(o3);
  ((ushort4*)(H + (size_t)b * NH))[tid] = wv;
}

// ---- final GEMV + sigmoid: one wave per row
__global__ __launch_bounds__(256) void out_kernel(
    const unsigned short* __restrict__ H, const float* __restrict__ Wout,
    const float* __restrict__ bout, float* __restrict__ out) {
  int wid = threadIdx.x >> 6, lane = threadIdx.x & 63;
  int b = (blockIdx.x << 2) | wid;
  const unsigned short* h = H + (size_t)b * NH + lane * 16;
  float s = 0.f;
#pragma unroll
  for (int i = 0; i < 16; ++i) s += bf2f(h[i]) * Wout[lane * 16 + i];
#pragma unroll
  for (int i = 1; i < 64; i <<= 1) s += __shfl_xor(s, i);
  if (lane == 0) out[b] = 1.f / (1.f + expf(-(s + bout[0])));
}

extern "C" void kernel_launch(void* const* d_in, const int* in_sizes, int n_in,
                              void* d_out, int out_size, void* d_ws, size_t ws_size,
                              hipStream_t stream) {
  const float* conts = (const float*)d_in[0];
  const int* cates = (const int*)d_in[1];
  const float* emb  = (const float*)d_in[3];
  const float* W1   = (const float*)d_in[4];
  const float* b1   = (const float*)d_in[5];
  const float* ln1g = (const float*)d_in[6];
  const float* ln1b = (const float*)d_in[7];
  const float* W2   = (const float*)d_in[8];
  const float* b2   = (const float*)d_in[9];
  const float* ln2g = (const float*)d_in[10];
  const float* ln2b = (const float*)d_in[11];
  const float* Wout = (const float*)d_in[12];
  const float* bout = (const float*)d_in[13];
  float* out = (float*)d_out;

  unsigned short* X   = (unsigned short*)d_ws;            // BATCH * K1P
  unsigned short* W1t = X + (size_t)BATCH * K1P;          // NH * K1P
  unsigned short* W2t = W1t + (size_t)NH * K1P;           // NH * NH
  unsigned short* H1  = W2t + (size_t)NH * NH;            // BATCH * NH
  unsigned short* H2  = H1 + (size_t)BATCH * NH;          // BATCH * NH
  float* Y = (float*)(H2 + (size_t)BATCH * NH);           // BATCH * NH f32

  hipLaunchKernelGGL(transpose_cast_kernel, dim3(K1P / 32, NH / 32), dim3(256), 0, stream,
                     W1, W1t, K1, NH, K1P);
  hipLaunchKernelGGL(transpose_cast_kernel, dim3(NH / 32, NH / 32), dim3(256), 0, stream,
                     W2, W2t, NH, NH, NH);
  hipLaunchKernelGGL(feature_kernel, dim3(BATCH / 4), dim3(256), 0, stream,
                     conts, cates, emb, X);
  hipLaunchKernelGGL(gemm_8ph, dim3((BATCH / 256) * (NH / 256)), dim3(512), 0, stream,
                     X, W1t, Y, K1P, K1P / 64);
  hipLaunchKernelGGL(ln_relu_kernel, dim3(BATCH), dim3(256), 0, stream,
                     Y, b1, ln1g, ln1b, H1);
  hipLaunchKernelGGL(gemm_8ph, dim3((BATCH / 256) * (NH / 256)), dim3(512), 0, stream,
                     H1, W2t, Y, NH, NH / 64);
  hipLaunchKernelGGL(ln_relu_kernel, dim3(BATCH), dim3(256), 0, stream,
                     Y, b2, ln2g, ln2b, H2);
  hipLaunchKernelGGL(out_kernel, dim3(BATCH / 4), dim3(256), 0, stream,
                     H2, Wout, bout, out);
}

// Round 3
// 201.283 us; speedup vs baseline: 1.7114x; 1.2201x over previous
//
#include <hip/hip_runtime.h>
#include <hip/hip_bf16.h>

#define BATCH 16384
#define NH 1024
#define NF 39
#define CCLD 72
#define KX 2432      // GEMM1 K: [0:13 conts][13:16 pad0][16:1680 cate flat][1680:2421 pairs][2421:2432 pad0]
#define NPAIR 741

typedef __attribute__((ext_vector_type(8))) short bf16x8;
typedef __attribute__((ext_vector_type(4))) float f32x4;

typedef const __attribute__((address_space(1))) unsigned int* gptr_t;
typedef __attribute__((address_space(3))) unsigned int* lptr_t;

__device__ __forceinline__ float bf2f(unsigned short u) {
  union { unsigned int i; float f; } c; c.i = ((unsigned int)u) << 16; return c.f;
}
__device__ __forceinline__ unsigned short f2bf(float f) {
  union { float f; unsigned int i; } c; c.f = f;
  unsigned int r = c.i + 0x7FFFu + ((c.i >> 16) & 1u);
  return (unsigned short)(r >> 16);
}

// ---- M13[f,n] = sum_d emb[f,d] * W1[f*64+d, n]  (collapses cont_emb K-block)
__global__ __launch_bounds__(256) void m13_kernel(
    const float* __restrict__ emb, const float* __restrict__ W1,
    float* __restrict__ M13) {
  int f = blockIdx.x;
  int n = blockIdx.y * 256 + threadIdx.x;
  float s = 0.f;
#pragma unroll 8
  for (int d = 0; d < 64; ++d)
    s += emb[f * 64 + d] * W1[(size_t)(f * 64 + d) * NH + n];
  M13[f * NH + n] = s;
}

// ---- W1t'(NH x KX bf16): row-remapped transpose of [M13 | W1 cate rows | W1 pair rows]
__global__ __launch_bounds__(256) void build_w1t_kernel(
    const float* __restrict__ W1, const float* __restrict__ M13,
    unsigned short* __restrict__ dst) {
  __shared__ float tile[32][33];
  int kb = blockIdx.x * 32, nb = blockIdx.y * 32;
  int tx = threadIdx.x & 31, ty = threadIdx.x >> 5;
#pragma unroll
  for (int i = 0; i < 32; i += 8) {
    int k = kb + ty + i;
    const float* src = nullptr;
    if (k < 13) src = M13 + (size_t)k * NH;
    else if (k >= 16 && k < 1680) src = W1 + (size_t)(832 + k - 16) * NH;
    else if (k >= 1680 && k < 1680 + NPAIR) src = W1 + (size_t)(2496 + k - 1680) * NH;
    tile[ty + i][tx] = src ? src[nb + tx] : 0.f;
  }
  __syncthreads();
#pragma unroll
  for (int i = 0; i < 32; i += 8)
    dst[(size_t)(nb + ty + i) * KX + kb + tx] = f2bf(tile[tx][ty + i]);
}

// ---- W transpose + bf16 cast (square, for W2)
__global__ __launch_bounds__(256) void transpose_cast_kernel(
    const float* __restrict__ src, unsigned short* __restrict__ dst,
    int K, int N, int Kpad) {
  __shared__ float tile[32][33];
  int kb = blockIdx.x * 32, nb = blockIdx.y * 32;
  int tx = threadIdx.x & 31, ty = threadIdx.x >> 5;
#pragma unroll
  for (int i = 0; i < 32; i += 8) {
    int k = kb + ty + i;
    tile[ty + i][tx] = (k < K) ? src[(size_t)k * N + nb + tx] : 0.f;
  }
  __syncthreads();
#pragma unroll
  for (int i = 0; i < 32; i += 8) {
    int n = nb + ty + i, k = kb + tx;
    dst[(size_t)n * Kpad + k] = f2bf(tile[tx][ty + i]);
  }
}

// ---- features -> X' rows: [conts 13 | 0 | cate flat 1664 | pairs 741 | 0]
__global__ __launch_bounds__(256) void feature_kernel(
    const float* __restrict__ conts, const int* __restrict__ cates,
    const float* __restrict__ emb, unsigned short* __restrict__ X) {
  __shared__ unsigned short cc[4][48 * CCLD];
  __shared__ unsigned short pb[4][752];
  int wid = threadIdx.x >> 6, lane = threadIdx.x & 63;
  int b = (blockIdx.x << 2) | wid;
  unsigned short* my = cc[wid];
  unsigned short* pw = pb[wid];
  unsigned short* Xrow = X + (size_t)b * KX;

#pragma unroll
  for (int f = 0; f < 13; ++f)
    my[f * CCLD + lane] = f2bf(emb[f * 64 + lane] * conts[b * 13 + f]);
#pragma unroll 2
  for (int j = 0; j < 26; ++j) {
    int idx = cates[b * 26 + j];
    my[(13 + j) * CCLD + lane] = f2bf(emb[(size_t)idx * 64 + lane]);
  }
#pragma unroll
  for (int f = NF; f < 48; ++f) my[f * CCLD + lane] = 0;
  if (lane < 16) Xrow[lane] = (lane < 13) ? f2bf(conts[b * 13 + lane]) : 0;
  if (lane < 752 - NPAIR) pw[NPAIR + lane] = 0;
  __syncthreads();

  // cate flat: 1664 shorts = 208 x bf16x8, vector copy LDS->global
#pragma unroll
  for (int i = 0; i < 4; ++i) {
    int q = i * 64 + lane;
    if (q < 208)
      *(bf16x8*)&Xrow[16 + q * 8] =
          *(const bf16x8*)&my[(13 + (q >> 3)) * CCLD + (q & 7) * 8];
  }

  // gram via MFMA (frag is both A and B operand)
  int r15 = lane & 15, hi = lane >> 4;
  bf16x8 fr[2][3];
#pragma unroll
  for (int t = 0; t < 3; ++t)
#pragma unroll
    for (int h = 0; h < 2; ++h)
      fr[h][t] = *(const bf16x8*)&my[(t * 16 + r15) * CCLD + h * 32 + hi * 8];

  f32x4 acc[3][3];
#pragma unroll
  for (int it = 0; it < 3; ++it)
#pragma unroll
    for (int jt = 0; jt < 3; ++jt)
      acc[it][jt] = (f32x4){0.f, 0.f, 0.f, 0.f};
#pragma unroll
  for (int h = 0; h < 2; ++h)
#pragma unroll
    for (int it = 0; it < 3; ++it)
#pragma unroll
      for (int jt = 0; jt < 3; ++jt)
        acc[it][jt] = __builtin_amdgcn_mfma_f32_16x16x32_bf16(
            fr[h][it], fr[h][jt], acc[it][jt], 0, 0, 0);

  // scatter pairs to LDS (C/D layout: col=lane&15, row=(lane>>4)*4+r)
#pragma unroll
  for (int it = 0; it < 3; ++it)
#pragma unroll
    for (int jt = 0; jt < 3; ++jt) {
      int g = jt * 16 + r15;
#pragma unroll
      for (int r = 0; r < 4; ++r) {
        int f = it * 16 + hi * 4 + r;
        if (f < g && g < NF) {
          int p = f * 38 - ((f * (f - 1)) >> 1) + g - f - 1;
          pw[p] = f2bf(acc[it][jt][r]);
        }
      }
    }
  __syncthreads();

  // pairs + tail pad: 752 shorts = 94 x bf16x8
#pragma unroll
  for (int i = 0; i < 2; ++i) {
    int q = i * 64 + lane;
    if (q < 94)
      *(bf16x8*)&Xrow[1680 + q * 8] = *(const bf16x8*)&pw[q * 8];
  }
}

// ===================== 256x256 8-phase GEMM (T1+T2+T3+T4+T5) =====================
// Hout(M x 1024 bf16) = A(M x K bf16) * Bt(1024 x K bf16)^T + bias. K mult of 64.

#define GLL(s_, d_) __builtin_amdgcn_global_load_lds((gptr_t)(s_), (lptr_t)(d_), 16, 0, 0)
#define RD(p_) (*(const bf16x8*)(p_))
#define DSTA(buf, h) (lds + (buf) * 32768 + (h) * 8192 + sd)
#define DSTB(buf, h) (lds + (buf) * 32768 + 16384 + (h) * 8192 + sd)
#define STG(dst, srcb, tau) do { \
    const unsigned short* _s = (srcb) + (size_t)(tau) * 64; \
    GLL(_s, dst); GLL(_s + (size_t)64 * K, (dst) + 4096); } while (0)
#define PHASE_BAR() do { \
    __builtin_amdgcn_s_barrier(); \
    asm volatile("s_waitcnt lgkmcnt(0)" ::: "memory"); \
    __builtin_amdgcn_sched_barrier(0); \
    __builtin_amdgcn_s_setprio(1); } while (0)
#define PHASE_END() do { \
    __builtin_amdgcn_s_setprio(0); \
    __builtin_amdgcn_s_barrier(); \
    __builtin_amdgcn_sched_barrier(0); } while (0)

__global__ __launch_bounds__(512, 2) void gemm_8ph(
    const unsigned short* __restrict__ A, const unsigned short* __restrict__ Bt,
    const float* __restrict__ bias, unsigned short* __restrict__ Hout,
    int K, int NT) {
  __shared__ unsigned short lds[65536];  // 128 KiB

  int bid = blockIdx.x;
  int swz = (bid & 7) * 32 + (bid >> 3);  // 256 wgs, 8 XCDs, chunked (bijective)
  int mb = swz >> 2, nb = swz & 3;
  size_t m0 = (size_t)mb * 256, n0 = (size_t)nb * 256;

  int tid = threadIdx.x, lane = tid & 63, w = tid >> 6;
  int wr = w >> 2, wc = w & 3;
  int r15 = lane & 15, hi = lane >> 4;

  int sr = tid >> 3;
  int ce = ((tid & 7) ^ (sr & 7)) << 3;   // inverse-swizzled global col group
  int sd = tid * 8;                        // linear LDS dest (shorts)
  const unsigned short* A0p = A + (m0 + sr) * (size_t)K + ce;
  const unsigned short* A1p = A0p + (size_t)128 * K;
  const unsigned short* B0p = Bt + (n0 + sr) * (size_t)K + ce;
  const unsigned short* B1p = B0p + (size_t)128 * K;

  int cbs = (((hi << 4) ^ ((r15 & 7) << 4)) >> 1);  // swizzled read col (shorts)
  int rb0 = r15 * 64 + cbs;
  int rb1 = rb0 ^ 32;
  const unsigned short* aH = lds + wr * 8192;
  const unsigned short* bH = lds + 16384 + (wc >> 1) * 8192 + (wc & 1) * 4096;

  f32x4 acc[8][4];
#pragma unroll
  for (int m = 0; m < 8; ++m)
#pragma unroll
    for (int n = 0; n < 4; ++n) acc[m][n] = (f32x4){0.f, 0.f, 0.f, 0.f};

  {
    int t1 = (NT > 1) ? 1 : 0;
    STG(DSTB(0, 0), B0p, 0);
    STG(DSTB(0, 1), B1p, 0);
    STG(DSTA(0, 0), A0p, 0);
    STG(DSTA(0, 1), A1p, 0);
    STG(DSTB(1, 0), B0p, t1);
    STG(DSTB(1, 1), B1p, t1);
    asm volatile("s_waitcnt vmcnt(4)" ::: "memory");
    __builtin_amdgcn_s_barrier();
    __builtin_amdgcn_sched_barrier(0);
  }

  bf16x8 aF[4][2], bF[4][2];

  for (int t = 0; t < NT; ++t) {
    int cur = t & 1, nxt = cur ^ 1;
    int ta = (t + 1 < NT) ? t + 1 : NT - 1;  // clamped dummies stay in-bounds
    int tb = (t + 2 < NT) ? t + 2 : NT - 1;
    const unsigned short* aB = aH + cur * 32768;
    const unsigned short* bB = bH + cur * 32768;

    // phase 0: read A0-3,B0-1; stage A-half0(t+1); MFMA (m0-3, n0-1)
#pragma unroll
    for (int i = 0; i < 4; ++i) {
      aF[i][0] = RD(aB + i * 1024 + rb0);
      aF[i][1] = RD(aB + i * 1024 + rb1);
    }
#pragma unroll
    for (int j = 0; j < 2; ++j) {
      bF[j][0] = RD(bB + j * 1024 + rb0);
      bF[j][1] = RD(bB + j * 1024 + rb1);
    }
    STG(DSTA(nxt, 0), A0p, ta);
    PHASE_BAR();
#pragma unroll
    for (int i = 0; i < 4; ++i)
#pragma unroll
      for (int j = 0; j < 2; ++j) {
        acc[i][j] = __builtin_amdgcn_mfma_f32_16x16x32_bf16(aF[i][0], bF[j][0], acc[i][j], 0, 0, 0);
        acc[i][j] = __builtin_amdgcn_mfma_f32_16x16x32_bf16(aF[i][1], bF[j][1], acc[i][j], 0, 0, 0);
      }
    PHASE_END();

    // phase 1: read B2-3; stage A-half1(t+1); MFMA (m0-3, n2-3)
#pragma unroll
    for (int j = 0; j < 2; ++j) {
      bF[2 + j][0] = RD(bB + (2 + j) * 1024 + rb0);
      bF[2 + j][1] = RD(bB + (2 + j) * 1024 + rb1);
    }
    STG(DSTA(nxt, 1), A1p, ta);
    PHASE_BAR();
#pragma unroll
    for (int i = 0; i < 4; ++i)
#pragma unroll
      for (int j = 0; j < 2; ++j) {
        acc[i][2 + j] = __builtin_amdgcn_mfma_f32_16x16x32_bf16(aF[i][0], bF[2 + j][0], acc[i][2 + j], 0, 0, 0);
        acc[i][2 + j] = __builtin_amdgcn_mfma_f32_16x16x32_bf16(aF[i][1], bF[2 + j][1], acc[i][2 + j], 0, 0, 0);
      }
    PHASE_END();

    // phase 2: read A4-7; stage B-half0(t+2); MFMA (m4-7, n2-3)
#pragma unroll
    for (int i = 0; i < 4; ++i) {
      aF[i][0] = RD(aB + (4 + i) * 1024 + rb0);
      aF[i][1] = RD(aB + (4 + i) * 1024 + rb1);
    }
    STG(DSTB(cur, 0), B0p, tb);
    PHASE_BAR();
#pragma unroll
    for (int i = 0; i < 4; ++i)
#pragma unroll
      for (int j = 0; j < 2; ++j) {
        acc[4 + i][2 + j] = __builtin_amdgcn_mfma_f32_16x16x32_bf16(aF[i][0], bF[2 + j][0], acc[4 + i][2 + j], 0, 0, 0);
        acc[4 + i][2 + j] = __builtin_amdgcn_mfma_f32_16x16x32_bf16(aF[i][1], bF[2 + j][1], acc[4 + i][2 + j], 0, 0, 0);
      }
    PHASE_END();

    // phase 3: stage B-half1(t+2); vmcnt(4); MFMA (m4-7, n0-1)
    STG(DSTB(cur, 1), B1p, tb);
    asm volatile("s_waitcnt vmcnt(4)" ::: "memory");
    PHASE_BAR();
#pragma unroll
    for (int i = 0; i < 4; ++i)
#pragma unroll
      for (int j = 0; j < 2; ++j) {
        acc[4 + i][j] = __builtin_amdgcn_mfma_f32_16x16x32_bf16(aF[i][0], bF[j][0], acc[4 + i][j], 0, 0, 0);
        acc[4 + i][j] = __builtin_amdgcn_mfma_f32_16x16x32_bf16(aF[i][1], bF[j][1], acc[4 + i][j], 0, 0, 0);
      }
    PHASE_END();
  }

  // epilogue: +bias, bf16 store. C/D: col=lane&15, row=(lane>>4)*4+q
  size_t crow = m0 + (size_t)wr * 128 + hi * 4;
  size_t ccol = n0 + (size_t)wc * 64 + r15;
  unsigned short* Hp = Hout + crow * NH + ccol;
  float bv[4];
#pragma unroll
  for (int n = 0; n < 4; ++n) bv[n] = bias[ccol + n * 16];
#pragma unroll
  for (int m = 0; m < 8; ++m)
#pragma unroll
    for (int n = 0; n < 4; ++n)
#pragma unroll
      for (int q = 0; q < 4; ++q)
        Hp[(size_t)(m * 16 + q) * NH + n * 16] = f2bf(acc[m][n][q] + bv[n]);
}

// ---- layernorm + relu (bf16 in -> bf16 out), one block per row
__global__ __launch_bounds__(256) void ln_relu_kernel(
    const unsigned short* __restrict__ Yb, const float* __restrict__ gamma,
    const float* __restrict__ beta, unsigned short* __restrict__ H) {
  int b = blockIdx.x, tid = threadIdx.x;
  ushort4 u = ((const ushort4*)(Yb + (size_t)b * NH))[tid];
  float v0 = bf2f(u.x), v1 = bf2f(u.y), v2 = bf2f(u.z), v3 = bf2f(u.w);
  float s1 = v0 + v1 + v2 + v3;
  float s2 = v0 * v0 + v1 * v1 + v2 * v2 + v3 * v3;
#pragma unroll
  for (int i = 1; i < 64; i <<= 1) {
    s1 += __shfl_xor(s1, i);
    s2 += __shfl_xor(s2, i);
  }
  __shared__ float a1[4], a2[4];
  int wid = tid >> 6, lane = tid & 63;
  if (lane == 0) { a1[wid] = s1; a2[wid] = s2; }
  __syncthreads();
  s1 = a1[0] + a1[1] + a1[2] + a1[3];
  s2 = a2[0] + a2[1] + a2[2] + a2[3];
  float mu = s1 * (1.0f / NH);
  float var = s2 * (1.0f / NH) - mu * mu;
  float rs = rsqrtf(var + 1e-5f);
  float4 gg = ((const float4*)gamma)[tid];
  float4 be = ((const float4*)beta)[tid];
  ushort4 wv;
  wv.x = f2bf(fmaxf((v0 - mu) * rs * gg.x + be.x, 0.f));
  wv.y = f2bf(fmaxf((v1 - mu) * rs * gg.y + be.y, 0.f));
  wv.z = f2bf(fmaxf((v2 - mu) * rs * gg.z + be.z, 0.f));
  wv.w = f2bf(fmaxf((v3 - mu) * rs * gg.w + be.w, 0.f));
  ((ushort4*)(H + (size_t)b * NH))[tid] = wv;
}

// ---- layernorm + relu + dot(Wout) + sigmoid, one block per row
__global__ __launch_bounds__(256) void ln_out_kernel(
    const unsigned short* __restrict__ Yb, const float* __restrict__ gamma,
    const float* __restrict__ beta, const float* __restrict__ Wout,
    const float* __restrict__ bout, float* __restrict__ out) {
  int b = blockIdx.x, tid = threadIdx.x;
  ushort4 u = ((const ushort4*)(Yb + (size_t)b * NH))[tid];
  float v0 = bf2f(u.x), v1 = bf2f(u.y), v2 = bf2f(u.z), v3 = bf2f(u.w);
  float s1 = v0 + v1 + v2 + v3;
  float s2 = v0 * v0 + v1 * v1 + v2 * v2 + v3 * v3;
#pragma unroll
  for (int i = 1; i < 64; i <<= 1) {
    s1 += __shfl_xor(s1, i);
    s2 += __shfl_xor(s2, i);
  }
  __shared__ float a1[4], a2[4], a3[4];
  int wid = tid >> 6, lane = tid & 63;
  if (lane == 0) { a1[wid] = s1; a2[wid] = s2; }
  __syncthreads();
  s1 = a1[0] + a1[1] + a1[2] + a1[3];
  s2 = a2[0] + a2[1] + a2[2] + a2[3];
  float mu = s1 * (1.0f / NH);
  float var = s2 * (1.0f / NH) - mu * mu;
  float rs = rsqrtf(var + 1e-5f);
  float4 gg = ((const float4*)gamma)[tid];
  float4 be = ((const float4*)beta)[tid];
  float o0 = fmaxf((v0 - mu) * rs * gg.x + be.x, 0.f);
  float o1 = fmaxf((v1 - mu) * rs * gg.y + be.y, 0.f);
  float o2 = fmaxf((v2 - mu) * rs * gg.z + be.z, 0.f);
  float o3 = fmaxf((v3 - mu) * rs * gg.w + be.w, 0.f);
  float4 wo = ((const float4*)Wout)[tid];
  float s = o0 * wo.x + o1 * wo.y + o2 * wo.z + o3 * wo.w;
#pragma unroll
  for (int i = 1; i < 64; i <<= 1) s += __shfl_xor(s, i);
  if (lane == 0) a3[wid] = s;
  __syncthreads();
  if (tid == 0) {
    float tot = a3[0] + a3[1] + a3[2] + a3[3];
    out[b] = 1.f / (1.f + expf(-(tot + bout[0])));
  }
}

extern "C" void kernel_launch(void* const* d_in, const int* in_sizes, int n_in,
                              void* d_out, int out_size, void* d_ws, size_t ws_size,
                              hipStream_t stream) {
  const float* conts = (const float*)d_in[0];
  const int* cates = (const int*)d_in[1];
  const float* emb  = (const float*)d_in[3];
  const float* W1   = (const float*)d_in[4];
  const float* b1   = (const float*)d_in[5];
  const float* ln1g = (const float*)d_in[6];
  const float* ln1b = (const float*)d_in[7];
  const float* W2   = (const float*)d_in[8];
  const float* b2   = (const float*)d_in[9];
  const float* ln2g = (const float*)d_in[10];
  const float* ln2b = (const float*)d_in[11];
  const float* Wout = (const float*)d_in[12];
  const float* bout = (const float*)d_in[13];
  float* out = (float*)d_out;

  unsigned short* X   = (unsigned short*)d_ws;            // BATCH * KX
  unsigned short* W1t = X + (size_t)BATCH * KX;           // NH * KX
  unsigned short* W2t = W1t + (size_t)NH * KX;            // NH * NH
  unsigned short* H1  = W2t + (size_t)NH * NH;            // BATCH * NH
  unsigned short* Yb1 = H1 + (size_t)BATCH * NH;          // BATCH * NH
  unsigned short* Yb2 = Yb1 + (size_t)BATCH * NH;         // BATCH * NH
  float* M13 = (float*)(Yb2 + (size_t)BATCH * NH);        // 13 * NH f32

  hipLaunchKernelGGL(m13_kernel, dim3(13, 4), dim3(256), 0, stream, emb, W1, M13);
  hipLaunchKernelGGL(build_w1t_kernel, dim3(KX / 32, NH / 32), dim3(256), 0, stream,
                     W1, M13, W1t);
  hipLaunchKernelGGL(transpose_cast_kernel, dim3(NH / 32, NH / 32), dim3(256), 0, stream,
                     W2, W2t, NH, NH, NH);
  hipLaunchKernelGGL(feature_kernel, dim3(BATCH / 4), dim3(256), 0, stream,
                     conts, cates, emb, X);
  hipLaunchKernelGGL(gemm_8ph, dim3(256), dim3(512), 0, stream,
                     X, W1t, b1, Yb1, KX, KX / 64);
  hipLaunchKernelGGL(ln_relu_kernel, dim3(BATCH), dim3(256), 0, stream,
                     Yb1, ln1g, ln1b, H1);
  hipLaunchKernelGGL(gemm_8ph, dim3(256), dim3(512), 0, stream,
                     H1, W2t, b2, Yb2, NH, NH / 64);
  hipLaunchKernelGGL(ln_out_kernel, dim3(BATCH), dim3(256), 0, stream,
                     Yb2, ln2g, ln2b, Wout, bout, out);
}